// Round 8
// baseline (564.765 us; speedup 1.0000x reference)
//
#include <hip/hip_runtime.h>
#include <hip/hip_bf16.h>
#include <math.h>

// Problem constants
#define NB 16
#define LL 2048
#define CC 512
#define HH 8
#define MM (NB*LL)          // 32768

typedef __attribute__((ext_vector_type(8))) short bf16x8;
typedef __attribute__((ext_vector_type(4))) float f32x4;
typedef __attribute__((ext_vector_type(8))) unsigned short u16x8;

// ---------------------------------------------------------------------------
// bf16 split helpers: x ≈ hi + lo, both bf16. Missing term lo*lo ~ 2^-18 rel.
// ---------------------------------------------------------------------------
__device__ inline unsigned short f2bf(float x) {
    __hip_bfloat16 b = __float2bfloat16(x);
    return __builtin_bit_cast(unsigned short, b);
}
__device__ inline float bf2f(unsigned short u) {
    __hip_bfloat16 b = __builtin_bit_cast(__hip_bfloat16, u);
    return __bfloat162float(b);
}
__device__ inline void split2(float x, unsigned short& h, unsigned short& l) {
    unsigned short hh = f2bf(x);
    float fh = bf2f(hh);
    h = hh;
    l = f2bf(x - fh);
}

// ---------------------------------------------------------------------------
// Prep: pack Wq/Wv hi/lo as [k>>3][c][k&7]; WpT same for virtual k 512..1023;
// Wbig (Wt folded into Wp) fp32 in same panel layout; cvec = bp + bt @ Wp^T.
// (Wk is no longer packed: k-projection eliminated; pooling uses Wk directly.)
// ---------------------------------------------------------------------------
__global__ __launch_bounds__(256)
void prep_kernel(const float* __restrict__ Wq, const float* __restrict__ Wv,
                 const float* __restrict__ Wt, const float* __restrict__ bt,
                 const float* __restrict__ Wp, const float* __restrict__ bp,
                 unsigned short* __restrict__ Bqh, unsigned short* __restrict__ Bql,
                 unsigned short* __restrict__ Bvh, unsigned short* __restrict__ Bvl,
                 unsigned short* __restrict__ WPTh, unsigned short* __restrict__ WPTl,
                 float* __restrict__ WBFP, float* __restrict__ cvec)
{
    const int t = blockIdx.x * 256 + threadIdx.x;   // 512*1024 threads
    const int c = t >> 10;         // output col n, 0..511
    const int k = t & 1023;        // virtual K, 0..1023
    unsigned short hh, ll;
    if (k < 512) {   // Wbig[k=h*64+d][c] = sum_e Wt[e][d] * Wp[c][h*64+e]
        const int h = k >> 6, d = k & 63;
        float s = 0.f;
        #pragma unroll 8
        for (int e = 0; e < 64; ++e) s += Wt[e * 64 + d] * Wp[c * CC + h * 64 + e];
        const size_t pq = (((size_t)(k >> 3) * 512) + c) * 8 + (k & 7);
        WBFP[pq] = s;          // fp32, gated per-sample later
        split2(Wq[c * CC + k], hh, ll); Bqh[pq] = hh; Bql[pq] = ll;
        split2(Wv[c * CC + k], hh, ll); Bvh[pq] = hh; Bvl[pq] = ll;
    } else {
        const int kl = k - 512;
        const size_t pw = (((size_t)(kl >> 3) * 512) + c) * 8 + (kl & 7);
        split2(Wp[c * CC + kl], hh, ll);
        WPTh[pw] = hh; WPTl[pw] = ll;
    }
    if (k == 0) {
        float cv = bp[c];
        for (int j = 0; j < 512; ++j) cv += bt[j & 63] * Wp[c * CC + j];
        cvec[c] = cv;
    }
}

// ---------------------------------------------------------------------------
// Uq[c*8+h] = sum_d Wq[(h*64+d)*512+c] * wqa[d];  qc[h] = bq_head.wqa + bqa
// ---------------------------------------------------------------------------
__global__ __launch_bounds__(512)
void uq_kernel(const float* __restrict__ Wq, const float* __restrict__ wqa,
               const float* __restrict__ bqa, const float* __restrict__ bq,
               float* __restrict__ Uq, float* __restrict__ qc)
{
    const int c = threadIdx.x;
    float u[8] = {0.f,0.f,0.f,0.f,0.f,0.f,0.f,0.f};
    for (int d = 0; d < 64; ++d) {
        const float wv = wqa[d];
        #pragma unroll
        for (int h = 0; h < 8; ++h) u[h] += Wq[((size_t)(h * 64 + d)) * 512 + c] * wv;
    }
    #pragma unroll
    for (int h = 0; h < 8; ++h) Uq[c * 8 + h] = u[h];
    if (c < 8) {
        float s = 0.f;
        for (int d = 0; d < 64; ++d) s += bq[c * 64 + d] * wqa[d];
        qc[c] = s + bqa[0];
    }
}

// ---------------------------------------------------------------------------
// Pool pass1 in x-space: per (n, chunk of 64 rows): for each row l compute
// 8 head scores s_h = x_l . U_h + cst_h, e=exp(s/8); accumulate e*x (per head,
// 512 channels) and sum(e). One read of x total per pool.
// ---------------------------------------------------------------------------
__global__ __launch_bounds__(256)
void pool_pass1(const float* __restrict__ x, const float* __restrict__ U, int ustride,
                const float* __restrict__ cst, int cstride, float* __restrict__ part)
{
    __shared__ float ps2[2][8][512];   // 32KB
    __shared__ float pe[4][8];
    const int n = blockIdx.x, ch = blockIdx.y;     // 16 x 32
    const int tid = threadIdx.x, wave = tid >> 6, lane = tid & 63;
    const int c8 = lane * 8;
    float u[64];
    {
        const float* Ub = U + (size_t)n * ustride + c8 * 8;
        #pragma unroll
        for (int j = 0; j < 16; ++j) *(float4*)&u[j * 4] = *(const float4*)&Ub[j * 4];
    }
    float cl[8];
    #pragma unroll
    for (int h = 0; h < 8; ++h) cl[h] = cst[n * cstride + h];
    float acc[64];
    #pragma unroll
    for (int j = 0; j < 64; ++j) acc[j] = 0.f;
    float ae[8] = {0.f,0.f,0.f,0.f,0.f,0.f,0.f,0.f};
    const int l0 = ch * 64 + wave * 16;
    const float* xb = x + ((size_t)n * LL + l0) * CC + c8;
    for (int it = 0; it < 16; ++it) {
        float xs[8];
        *(float4*)&xs[0] = *(const float4*)&xb[(size_t)it * CC];
        *(float4*)&xs[4] = *(const float4*)&xb[(size_t)it * CC + 4];
        #pragma unroll
        for (int h = 0; h < 8; ++h) {
            float s = xs[0]*u[h]    + xs[1]*u[8+h]  + xs[2]*u[16+h] + xs[3]*u[24+h]
                    + xs[4]*u[32+h] + xs[5]*u[40+h] + xs[6]*u[48+h] + xs[7]*u[56+h];
            s += __shfl_xor(s, 1, 64);  s += __shfl_xor(s, 2, 64);
            s += __shfl_xor(s, 4, 64);  s += __shfl_xor(s, 8, 64);
            s += __shfl_xor(s, 16, 64); s += __shfl_xor(s, 32, 64);
            const float e = __expf((s + cl[h]) * 0.125f);
            ae[h] += e;
            #pragma unroll
            for (int j = 0; j < 8; ++j) acc[h * 8 + j] += e * xs[j];
        }
    }
    if (wave < 2) {
        #pragma unroll
        for (int h = 0; h < 8; ++h)
            #pragma unroll
            for (int j = 0; j < 8; ++j) ps2[wave][h][c8 + j] = acc[h * 8 + j];
    }
    if (lane == 0) {
        #pragma unroll
        for (int h = 0; h < 8; ++h) pe[wave][h] = ae[h];
    }
    __syncthreads();
    if (wave >= 2) {
        #pragma unroll
        for (int h = 0; h < 8; ++h)
            #pragma unroll
            for (int j = 0; j < 8; ++j) ps2[wave - 2][h][c8 + j] += acc[h * 8 + j];
    }
    __syncthreads();
    float* pb = part + ((size_t)(n * 32 + ch)) * 4104;
    for (int q = tid; q < 4096; q += 256) {
        const int h = q >> 9, c = q & 511;
        pb[q] = ps2[0][h][c] + ps2[1][h][c];
    }
    if (tid < 8) pb[4096 + tid] = pe[0][tid] + pe[1][tid] + pe[2][tid] + pe[3][tid];
}

// ---------------------------------------------------------------------------
// Pool combine. mode 0 (q): pooled_q = PX.Wq_row/den + bq; gq = pooled*wka;
// then Uk[n][c*8+h] = sum_d Wk[(h64+d)*512+c]*gq, kc[n][h] = bk_head.gq + bka.
// mode 1 (k): pk[n][h*64+d] = PX.Wk_row/den + bk.
// ---------------------------------------------------------------------------
__global__ __launch_bounds__(512)
void pool_combine(const float* __restrict__ part,
                  const float* __restrict__ W1, const float* __restrict__ b1,
                  const float* __restrict__ wka,
                  const float* __restrict__ Wk, const float* __restrict__ bk,
                  const float* __restrict__ bka,
                  float* __restrict__ gq, float* __restrict__ Uk,
                  float* __restrict__ kc, float* __restrict__ pk, int mode)
{
    __shared__ float px[8][512];
    __shared__ float inv[8];
    __shared__ float gql[8][64];
    const int n = blockIdx.x;
    const int tid = threadIdx.x;
    const float* pbase = part + (size_t)n * 32 * 4104;
    for (int q = tid; q < 4096; q += 512) {
        float s = 0.f;
        for (int c2 = 0; c2 < 32; ++c2) s += pbase[(size_t)c2 * 4104 + q];
        px[q >> 9][q & 511] = s;
    }
    if (tid < 8) {
        float s = 0.f;
        for (int c2 = 0; c2 < 32; ++c2) s += pbase[(size_t)c2 * 4104 + 4096 + tid];
        inv[tid] = 1.f / s;
    }
    __syncthreads();
    const int h = tid >> 6, d = tid & 63;
    const int row = h * 64 + d;
    float s = 0.f;
    const float* wr = W1 + (size_t)row * 512;
    #pragma unroll 8
    for (int c = 0; c < 512; ++c) s += px[h][c] * wr[c];
    const float pooled = s * inv[h] + b1[row];
    if (mode == 0) {
        const float g = pooled * wka[d];
        gq[n * 512 + row] = g;
        gql[h][d] = g;
        __syncthreads();
        const int c = tid & 511;
        float uk[8];
        #pragma unroll
        for (int hh = 0; hh < 8; ++hh) uk[hh] = 0.f;
        for (int dd = 0; dd < 64; ++dd) {
            #pragma unroll
            for (int hh = 0; hh < 8; ++hh)
                uk[hh] += Wk[((size_t)(hh * 64 + dd)) * 512 + c] * gql[hh][dd];
        }
        #pragma unroll
        for (int hh = 0; hh < 8; ++hh) Uk[(size_t)n * 4096 + c * 8 + hh] = uk[hh];
        if (tid < 8) {
            float kcv = 0.f;
            for (int dd = 0; dd < 64; ++dd) kcv += bk[tid * 64 + dd] * gql[tid][dd];
            kc[n * 8 + tid] = kcv + bka[0];
        }
    } else {
        pk[n * 512 + row] = pooled;
    }
}

// ---------------------------------------------------------------------------
// Per-sample B-gate: WBG[smp] = diag(pk[smp]) * Wbig, split hi/lo, packed.
// ---------------------------------------------------------------------------
__global__ __launch_bounds__(256)
void gate_wb(const float* __restrict__ WBFP, const float* __restrict__ pk,
             unsigned short* __restrict__ WBGh, unsigned short* __restrict__ WBGl)
{
    const int u = blockIdx.x * 256 + threadIdx.x;   // 524288
    const int smp = u >> 15;
    const int r = u & 32767;
    const int kp = r >> 9, c = r & 511;
    const float* w = &WBFP[(((size_t)kp * 512) + c) * 8];
    const float* p = &pk[smp * 512 + kp * 8];
    u16x8 hv, lv;
    #pragma unroll
    for (int j = 0; j < 8; ++j) {
        unsigned short h, lo;
        split2(w[j] * p[j], h, lo);
        hv[j] = h; lv[j] = lo;
    }
    const size_t o = (((size_t)smp * 64 + kp) * 512 + c) * 8;
    *(u16x8*)&WBGh[o] = hv;
    *(u16x8*)&WBGl[o] = lv;
}

// ---------------------------------------------------------------------------
// Projection GEMM (proven r7): fp32 A staged+split in-kernel, packed hi/lo
// bf16 OUTPUT in [c>>3][m][c&7] layout via LDS-bounce epilogue.
// BM=128, BN=256, BK=32, 8 waves. Virtual nt: type selects slot0/slot1.
// ---------------------------------------------------------------------------
__global__ __launch_bounds__(512, 4)
void gemm_proj(const float* __restrict__ A0, const float* __restrict__ A1,
               const unsigned short* __restrict__ B0h, const unsigned short* __restrict__ B0l,
               const unsigned short* __restrict__ B1h, const unsigned short* __restrict__ B1l,
               const float* __restrict__ bias0, const float* __restrict__ bias1,
               unsigned short* __restrict__ O0h, unsigned short* __restrict__ O0l,
               unsigned short* __restrict__ O1h, unsigned short* __restrict__ O1l,
               int ntl)
{
    __shared__ __align__(16) unsigned short smem[24576];   // 48KB
    unsigned short* sAh = smem;
    unsigned short* sAl = smem + 4096;
    unsigned short* sBh = smem + 8192;
    unsigned short* sBl = smem + 16384;

    const int tid = threadIdx.x;
    const int flat = blockIdx.x;
    const int xcd = flat & 7, idx = flat >> 3;
    const int mt = xcd * 32 + (idx >> ntl);
    const int ntv = idx & ((1 << ntl) - 1);
    const int type = ntv >> 1;
    const int n0 = (ntv & 1) * 256;
    const int m0 = mt * 128;
    const int l = tid & 63, w = tid >> 6;
    const int wm = w >> 2, wn = w & 3;

    const float* Asrc = type ? A1 : A0;
    const unsigned short* Bh = type ? B1h : B0h;
    const unsigned short* Bl = type ? B1l : B0l;
    const float* bias = type ? bias1 : bias0;
    unsigned short* Oh = type ? O1h : O0h;
    unsigned short* Ol = type ? O1l : O0l;

    const int arow = tid & 127, akp = tid >> 7;
    const int bcol = tid & 255, bkp0 = tid >> 8;

    f32x4 acc[4][4] = {};

    float4 pa0, pa1;
    uint4 pbh0, pbh1, pbl0, pbl1;

    auto loadTile = [&](int kt) {
        const int k0 = kt * 32;
        const float* p = Asrc + (size_t)(m0 + arow) * CC + k0 + akp * 8;
        pa0 = *(const float4*)p; pa1 = *(const float4*)(p + 4);
        const int kpg = kt * 4;
        const size_t ob0 = (((size_t)(kpg + bkp0) * 512) + n0 + bcol) * 8;
        const size_t ob1 = (((size_t)(kpg + bkp0 + 2) * 512) + n0 + bcol) * 8;
        pbh0 = *(const uint4*)&Bh[ob0]; pbh1 = *(const uint4*)&Bh[ob1];
        pbl0 = *(const uint4*)&Bl[ob0]; pbl1 = *(const uint4*)&Bl[ob1];
    };

    auto storeTile = [&]() {
        float x[8];
        *(float4*)&x[0] = pa0; *(float4*)&x[4] = pa1;
        u16x8 hv, lv;
        #pragma unroll
        for (int j = 0; j < 8; ++j) { unsigned short h, lo; split2(x[j], h, lo); hv[j] = h; lv[j] = lo; }
        *(u16x8*)&sAh[(akp * 128 + arow) * 8] = hv;
        *(u16x8*)&sAl[(akp * 128 + arow) * 8] = lv;
        *(uint4*)&sBh[(bkp0 * 256 + bcol) * 8] = pbh0;
        *(uint4*)&sBh[((bkp0 + 2) * 256 + bcol) * 8] = pbh1;
        *(uint4*)&sBl[(bkp0 * 256 + bcol) * 8] = pbl0;
        *(uint4*)&sBl[((bkp0 + 2) * 256 + bcol) * 8] = pbl1;
    };

    loadTile(0);

    for (int kt = 0; kt < 16; ++kt) {
        __syncthreads();
        storeTile();
        __syncthreads();
        if (kt + 1 < 16) loadTile(kt + 1);

        const int g = l >> 4;
        const int rA = wm * 64 + (l & 15);
        const int rB = wn * 64 + (l & 15);
        const bf16x8* vAh = (const bf16x8*)sAh; const bf16x8* vAl = (const bf16x8*)sAl;
        const bf16x8* vBh = (const bf16x8*)sBh; const bf16x8* vBl = (const bf16x8*)sBl;
        bf16x8 ah[4], al[4], bh[4], bl[4];
        #pragma unroll
        for (int f = 0; f < 4; ++f) {
            ah[f] = vAh[g * 128 + rA + f * 16];
            al[f] = vAl[g * 128 + rA + f * 16];
            bh[f] = vBh[g * 256 + rB + f * 16];
            bl[f] = vBl[g * 256 + rB + f * 16];
        }
        #pragma unroll
        for (int i = 0; i < 4; ++i)
            #pragma unroll
            for (int j = 0; j < 4; ++j) {
                acc[i][j] = __builtin_amdgcn_mfma_f32_16x16x32_bf16(ah[i], bh[j], acc[i][j], 0, 0, 0);
                acc[i][j] = __builtin_amdgcn_mfma_f32_16x16x32_bf16(ah[i], bl[j], acc[i][j], 0, 0, 0);
                acc[i][j] = __builtin_amdgcn_mfma_f32_16x16x32_bf16(al[i], bh[j], acc[i][j], 0, 0, 0);
            }
    }

    // Packed epilogue via LDS bounce (proven r7).
    const int rowb = (l >> 4) * 4, colb = l & 15;
    const int hw = wn >> 1;
    const int clbase = (wn & 1) * 64;
    unsigned short* sP = smem;
    for (int half = 0; half < 2; ++half) {
        for (int part = 0; part < 2; ++part) {
            __syncthreads();
            if (hw == half) {
                #pragma unroll
                for (int j = 0; j < 4; ++j) {
                    const float bv = bias[n0 + half * 128 + clbase + j * 16 + colb];
                    #pragma unroll
                    for (int i = 0; i < 4; ++i) {
                        #pragma unroll
                        for (int e = 0; e < 4; ++e) {
                            const int row = wm * 64 + i * 16 + rowb + e;
                            const int cl = clbase + j * 16 + colb;
                            unsigned short h, lo;
                            split2(acc[i][j][e] + bv, h, lo);
                            sP[row * 132 + cl] = part ? lo : h;
                        }
                    }
                }
            }
            __syncthreads();
            unsigned short* OP = part ? Ol : Oh;
            #pragma unroll
            for (int pass = 0; pass < 4; ++pass) {
                const int o = pass * 4 + (tid >> 7);
                const int row = tid & 127;
                const uint2 v0 = *(const uint2*)&sP[row * 132 + o * 8];
                const uint2 v1 = *(const uint2*)&sP[row * 132 + o * 8 + 4];
                const int cg = n0 + half * 128 + o * 8;
                uint4 val; val.x = v0.x; val.y = v0.y; val.z = v1.x; val.w = v1.y;
                *(uint4*)&OP[((size_t)(cg >> 3) * MM + m0 + row) * 8] = val;
            }
        }
    }
}

// ---------------------------------------------------------------------------
// Final GEMM (proven r7): packed bf16 A (VP then QP), B = WBG[smp] then WPT.
// ---------------------------------------------------------------------------
__global__ __launch_bounds__(512, 4)
void gemm_final(const unsigned short* __restrict__ VPh, const unsigned short* __restrict__ VPl,
                const unsigned short* __restrict__ QPh, const unsigned short* __restrict__ QPl,
                const unsigned short* __restrict__ WBGh, const unsigned short* __restrict__ WBGl,
                const unsigned short* __restrict__ WPTh, const unsigned short* __restrict__ WPTl,
                const float* __restrict__ cvec, float* __restrict__ out)
{
    __shared__ __align__(16) unsigned short smem[24576];
    unsigned short* sAh = smem;
    unsigned short* sAl = smem + 4096;
    unsigned short* sBh = smem + 8192;
    unsigned short* sBl = smem + 16384;

    const int tid = threadIdx.x;
    const int flat = blockIdx.x;
    const int xcd = flat & 7, idx = flat >> 3;
    const int mt = xcd * 32 + (idx >> 1);
    const int nt = idx & 1;
    const int n0 = nt * 256, m0 = mt * 128;
    const int l = tid & 63, w = tid >> 6;
    const int wm = w >> 2, wn = w & 3;
    const int smp = mt >> 4;

    const int arow = tid & 127, akp = tid >> 7;
    const int bcol = tid & 255, bkp0 = tid >> 8;

    f32x4 acc[4][4] = {};

    uint4 pah, pal, pbh0, pbh1, pbl0, pbl1;

    auto loadTile = [&](int kt) {
        const int ktl = kt & 15;
        const unsigned short* Ah_ = (kt < 16) ? VPh : QPh;
        const unsigned short* Al_ = (kt < 16) ? VPl : QPl;
        const size_t ao = (((size_t)ktl * 4 + akp) * MM + m0 + arow) * 8;
        pah = *(const uint4*)&Ah_[ao];
        pal = *(const uint4*)&Al_[ao];
        const unsigned short* Bh_;
        const unsigned short* Bl_;
        size_t bb;
        if (kt < 16) { Bh_ = WBGh + (size_t)smp * 262144; Bl_ = WBGl + (size_t)smp * 262144; bb = kt * 4; }
        else         { Bh_ = WPTh; Bl_ = WPTl; bb = (kt - 16) * 4; }
        const size_t ob0 = ((bb + bkp0) * 512 + n0 + bcol) * 8;
        const size_t ob1 = ((bb + bkp0 + 2) * 512 + n0 + bcol) * 8;
        pbh0 = *(const uint4*)&Bh_[ob0]; pbh1 = *(const uint4*)&Bh_[ob1];
        pbl0 = *(const uint4*)&Bl_[ob0]; pbl1 = *(const uint4*)&Bl_[ob1];
    };

    auto storeTile = [&]() {
        *(uint4*)&sAh[(akp * 128 + arow) * 8] = pah;
        *(uint4*)&sAl[(akp * 128 + arow) * 8] = pal;
        *(uint4*)&sBh[(bkp0 * 256 + bcol) * 8] = pbh0;
        *(uint4*)&sBh[((bkp0 + 2) * 256 + bcol) * 8] = pbh1;
        *(uint4*)&sBl[(bkp0 * 256 + bcol) * 8] = pbl0;
        *(uint4*)&sBl[((bkp0 + 2) * 256 + bcol) * 8] = pbl1;
    };

    loadTile(0);

    for (int kt = 0; kt < 32; ++kt) {
        __syncthreads();
        storeTile();
        __syncthreads();
        if (kt + 1 < 32) loadTile(kt + 1);

        const int g = l >> 4;
        const int rA = wm * 64 + (l & 15);
        const int rB = wn * 64 + (l & 15);
        const bf16x8* vAh = (const bf16x8*)sAh; const bf16x8* vAl = (const bf16x8*)sAl;
        const bf16x8* vBh = (const bf16x8*)sBh; const bf16x8* vBl = (const bf16x8*)sBl;
        bf16x8 ah[4], al[4], bh[4], bl[4];
        #pragma unroll
        for (int f = 0; f < 4; ++f) {
            ah[f] = vAh[g * 128 + rA + f * 16];
            al[f] = vAl[g * 128 + rA + f * 16];
            bh[f] = vBh[g * 256 + rB + f * 16];
            bl[f] = vBl[g * 256 + rB + f * 16];
        }
        #pragma unroll
        for (int i = 0; i < 4; ++i)
            #pragma unroll
            for (int j = 0; j < 4; ++j) {
                acc[i][j] = __builtin_amdgcn_mfma_f32_16x16x32_bf16(ah[i], bh[j], acc[i][j], 0, 0, 0);
                acc[i][j] = __builtin_amdgcn_mfma_f32_16x16x32_bf16(ah[i], bl[j], acc[i][j], 0, 0, 0);
                acc[i][j] = __builtin_amdgcn_mfma_f32_16x16x32_bf16(al[i], bh[j], acc[i][j], 0, 0, 0);
            }
    }

    const int rowb = (l >> 4) * 4, colb = l & 15;
    #pragma unroll
    for (int j = 0; j < 4; ++j) {
        const int c = n0 + wn * 64 + j * 16 + colb;
        const float bv = cvec[c];
        #pragma unroll
        for (int i = 0; i < 4; ++i) {
            const int r = m0 + wm * 64 + i * 16 + rowb;
            #pragma unroll
            for (int e = 0; e < 4; ++e)
                out[(size_t)(r + e) * CC + c] = acc[i][j][e] + bv;
        }
    }
}

// ---------------------------------------------------------------------------
// ws byte offsets (~156 MB total; <= 198MB envelope proven in r2)
// ---------------------------------------------------------------------------
#define OFF_BQH   0ull
#define OFF_BQL   524288ull
#define OFF_BVH   1048576ull
#define OFF_BVL   1572864ull
#define OFF_WPTH  2097152ull
#define OFF_WPTL  2621440ull
#define OFF_WBFP  3145728ull       // 1MB fp32 Wbig (panel layout)
#define OFF_CVEC  4194304ull
#define OFF_UQ    4198400ull       // 4096 f
#define OFF_QC    4214784ull       // 8 f
#define OFF_UK    4215040ull       // 16*4096 f
#define OFF_KC    4477184ull       // 16*8 f
#define OFF_GQ    4477952ull       // 16*512 f
#define OFF_PK    4510720ull       // 16*512 f
#define OFF_PART  4543488ull       // 16*32*4104 f = 8404992 B
#define OFF_WBGH  13107200ull      // 8MB
#define OFF_WBGL  21495808ull      // 8MB
#define OFF_QPH   29884416ull      // 32MB
#define OFF_QPL   63438848ull      // 32MB
#define OFF_VPH   96993280ull      // 32MB
#define OFF_VPL   130547712ull     // 32MB

extern "C" void kernel_launch(void* const* d_in, const int* in_sizes, int n_in,
                              void* d_out, int out_size, void* d_ws, size_t ws_size,
                              hipStream_t stream) {
    const float* x_q  = (const float*)d_in[0];
    const float* x_kv = (const float*)d_in[1];
    const float* Wq   = (const float*)d_in[2];
    const float* bq   = (const float*)d_in[3];
    const float* wqa  = (const float*)d_in[4];
    const float* bqa  = (const float*)d_in[5];
    const float* Wk   = (const float*)d_in[6];
    const float* bk   = (const float*)d_in[7];
    const float* wka  = (const float*)d_in[8];
    const float* bka  = (const float*)d_in[9];
    const float* Wv   = (const float*)d_in[10];
    const float* bv   = (const float*)d_in[11];
    const float* Wt   = (const float*)d_in[12];
    const float* bt   = (const float*)d_in[13];
    const float* Wp   = (const float*)d_in[14];
    const float* bp   = (const float*)d_in[15];
    float* out = (float*)d_out;
    char* ws = (char*)d_ws;

    unsigned short* Bqh  = (unsigned short*)(ws + OFF_BQH);
    unsigned short* Bql  = (unsigned short*)(ws + OFF_BQL);
    unsigned short* Bvh  = (unsigned short*)(ws + OFF_BVH);
    unsigned short* Bvl  = (unsigned short*)(ws + OFF_BVL);
    unsigned short* WPTh = (unsigned short*)(ws + OFF_WPTH);
    unsigned short* WPTl = (unsigned short*)(ws + OFF_WPTL);
    float* WBFP = (float*)(ws + OFF_WBFP);
    float* cvec = (float*)(ws + OFF_CVEC);
    float* Uq   = (float*)(ws + OFF_UQ);
    float* qc   = (float*)(ws + OFF_QC);
    float* Uk   = (float*)(ws + OFF_UK);
    float* kc   = (float*)(ws + OFF_KC);
    float* gq   = (float*)(ws + OFF_GQ);
    float* pk   = (float*)(ws + OFF_PK);
    float* part = (float*)(ws + OFF_PART);
    unsigned short* WBGh = (unsigned short*)(ws + OFF_WBGH);
    unsigned short* WBGl = (unsigned short*)(ws + OFF_WBGL);
    unsigned short* QPh  = (unsigned short*)(ws + OFF_QPH);
    unsigned short* QPl  = (unsigned short*)(ws + OFF_QPL);
    unsigned short* VPh  = (unsigned short*)(ws + OFF_VPH);
    unsigned short* VPl  = (unsigned short*)(ws + OFF_VPL);

    const dim3 pgrid(NB, 32);

    // 1. weight prep (Wq/Wv/WpT packed + Wbig fp32 + cvec)
    prep_kernel<<<2048, 256, 0, stream>>>(Wq, Wv, Wt, bt, Wp, bp,
                                          Bqh, Bql, Bvh, Bvl, WPTh, WPTl, WBFP, cvec);
    // 2. Uq, qc (tiny)
    uq_kernel<<<1, 512, 0, stream>>>(Wq, wqa, bqa, bq, Uq, qc);
    // 3. q-pool in x-space (one pass over x_q)
    pool_pass1<<<pgrid, 256, 0, stream>>>(x_q, Uq, 0, qc, 0, part);
    pool_combine<<<NB, 512, 0, stream>>>(part, Wq, bq, wka, Wk, bk, bka,
                                         gq, Uk, kc, nullptr, 0);
    // 4. k-pool in x-space (one pass over x_kv) -> pooled_k; K-projection deleted
    pool_pass1<<<pgrid, 256, 0, stream>>>(x_kv, Uk, 4096, kc, 8, part);
    pool_combine<<<NB, 512, 0, stream>>>(part, Wk, bk, nullptr, nullptr, nullptr, nullptr,
                                         nullptr, nullptr, nullptr, pk, 1);
    // 5. fold gate into B: WBG[smp] = diag(pk) * Wbig
    gate_wb<<<2048, 256, 0, stream>>>(WBFP, pk, WBGh, WBGl);
    // 6. fused Q+V projections (packed hi/lo outputs)
    gemm_proj<<<1024, 512, 0, stream>>>(x_q, x_kv, Bqh, Bql, Bvh, Bvl, bq, bv,
                                        QPh, QPl, VPh, VPl, 2);
    // 7. final: v@WBG[smp] + q@WpT + cvec
    gemm_final<<<512, 512, 0, stream>>>(VPh, VPl, QPh, QPl, WBGh, WBGl,
                                        WPTh, WPTl, cvec, out);
}